// Round 5
// baseline (98.773 us; speedup 1.0000x reference)
//
#include <hip/hip_runtime.h>
#include <hip/hip_bf16.h>

// world_state_encoder: out[b, beaker*4+slot, :] = color_emb[X[b, beaker*5+1+slot], :]
// B=32768, 7 beakers, 4 color slots, D=128 -> out is [B, 3584] f32.
// Write-BW bound: ~470 MB out vs 4.6 MB idx in. Demonstrated ceiling on this
// chip: harness memset (fillBufferAligned) hits 6.8-7.0 TB/s -> floor ~70 us.
//
// R3 (LDS-staged indices, barrier-free store loop, unroll 8): 96.8 us =
// 4.85 TB/s. Latency and issue-rate arithmetic both say those aren't the
// limit at 28 waves/CU.
// R5 (= R4 fixed): nontemporal output stores. The 470 MB write-only stream
// was allocating dirty lines in the 32 MB L2 and churning evictions; the
// fill kernel that hits 6.9 TB/s streams past L2. Emit output stores as
// __builtin_nontemporal_store. NOTE: the builtin rejects HIP's float4
// (HIP_vector_type class) -- use a native clang ext_vector f32x4 instead.

#define NUM_BEAKERS 7
#define ENTRIES_PER_BEAKER 5
#define ROW_INTS (NUM_BEAKERS * ENTRIES_PER_BEAKER)   // 35
#define COLOR_DIM 128
#define GROUPS 28                                     // 7 beakers * 4 color slots
#define F4_PER_ROW (GROUPS * COLOR_DIM / 4)           // 28*32 = 896 float4 per row
#define NTHREADS F4_PER_ROW                           // 896 = 14 waves
#define CHUNK 64                                      // rows per block

typedef float f32x4 __attribute__((ext_vector_type(4)));   // native clang vector

__global__ __launch_bounds__(NTHREADS, 7) void world_state_encoder_kernel(
        const int* __restrict__ X,          // [B, 35] int32
        const float* __restrict__ emb,      // [7, 128] f32
        float* __restrict__ out,            // [B, 3584] f32
        int B) {
    const int t  = threadIdx.x;             // 0..895
    const int g  = t >> 5;                  // gathered-vector index 0..27
    const int d4 = t & 31;                  // float4 index within the 128-f32 vector
    const int xoff = (g >> 2) * ENTRIES_PER_BEAKER + (g & 3) + 1;  // within a 35-int row

    __shared__ int xs[CHUNK * ROW_INTS];    // 8960 B raw X slice for this chunk

    const f32x4* __restrict__ embf4 = reinterpret_cast<const f32x4*>(emb);
    f32x4* __restrict__ outf4 = reinterpret_cast<f32x4*>(out);

    for (int b0 = blockIdx.x * CHUNK; b0 < B; b0 += gridDim.x * CHUNK) {
        const int rows  = min(CHUNK, B - b0);
        const int nints = rows * ROW_INTS;

        __syncthreads();                    // xs reuse guard (no-op on first pass)
        for (int i = t; i < nints; i += NTHREADS)
            xs[i] = X[b0 * ROW_INTS + i];   // one coalesced 8960 B read
        __syncthreads();

        f32x4* __restrict__ dst = outf4 + (size_t)b0 * F4_PER_ROW + t;
        #pragma unroll 8
        for (int r = 0; r < rows; ++r) {
            const int id = xs[r * ROW_INTS + xoff];        // LDS broadcast
            const f32x4 v = embf4[id * (COLOR_DIM / 4) + d4];  // L1 hit (3.5 KB table)
            __builtin_nontemporal_store(v, dst + (size_t)r * F4_PER_ROW);  // nt store
        }
    }
}

extern "C" void kernel_launch(void* const* d_in, const int* in_sizes, int n_in,
                              void* d_out, int out_size, void* d_ws, size_t ws_size,
                              hipStream_t stream) {
    const int*   X   = (const int*)d_in[0];     // [B, 35] int32
    const float* emb = (const float*)d_in[1];   // [7, 128] f32
    float*       out = (float*)d_out;           // [B, 3584] f32

    const int B = in_sizes[0] / ROW_INTS;       // 32768

    const int nchunks = (B + CHUNK - 1) / CHUNK;    // 512 for B=32768
    const int grid = (nchunks < 512) ? nchunks : 512;
    world_state_encoder_kernel<<<grid, NTHREADS, 0, stream>>>(X, emb, out, B);
}

// Round 6
// 97.044 us; speedup vs baseline: 1.0178x; 1.0178x over previous
//
#include <hip/hip_runtime.h>
#include <hip/hip_bf16.h>

// world_state_encoder: out[b, beaker*4+slot, :] = color_emb[X[b, beaker*5+1+slot], :]
// B=32768, 7 beakers, 4 color slots, D=128 -> out is [B, 3584] f32.
// Write-BW bound: ~470 MB out vs 4.6 MB idx in. Demonstrated ceiling:
// harness memset = 6.8-7.0 TB/s (floor ~70 us). R3 = 96.8 us (4.85 TB/s),
// R5 nt-stores = 98.8 us (neutral -> L2 write-alloc theory dead).
//
// R6: NO VMEM LOADS in the store loop. Loads and stores share the in-order
// vmcnt counter, so consuming the in-loop emb global_load forced a full
// drain of all older in-flight stores every unroll group -- the store
// pipeline restarted from empty every 8 rows (memset never drains, hence
// 6.9 TB/s). Fix: stage emb (7x128 f32 = 3584 B = exactly one f32 per
// thread) into LDS once; inner loop is ds_read(id) + ds_read_b128(emb) +
// global_store only. Only remaining vmcnt waits are register-rotation waits
// on the OLDEST store (depth-8 pipeline/wave = ~229 KB in flight per CU).
// LDS emb read: each 16-lane quarter reads 256 contiguous B -> 2-way
// aliasing = free (m136).

#define NUM_BEAKERS 7
#define ENTRIES_PER_BEAKER 5
#define ROW_INTS (NUM_BEAKERS * ENTRIES_PER_BEAKER)   // 35
#define COLOR_DIM 128
#define GROUPS 28                                     // 7 beakers * 4 color slots
#define F4_PER_ROW (GROUPS * COLOR_DIM / 4)           // 28*32 = 896 float4 per row
#define NTHREADS F4_PER_ROW                           // 896 = 14 waves
#define CHUNK 64                                      // rows per block

typedef float f32x4 __attribute__((ext_vector_type(4)));

__global__ __launch_bounds__(NTHREADS, 7) void world_state_encoder_kernel(
        const int* __restrict__ X,          // [B, 35] int32
        const float* __restrict__ emb,      // [7, 128] f32
        float* __restrict__ out,            // [B, 3584] f32
        int B) {
    const int t  = threadIdx.x;             // 0..895
    const int g  = t >> 5;                  // gathered-vector index 0..27
    const int d4 = t & 31;                  // float4 index within the 128-f32 vector
    const int xoff = (g >> 2) * ENTRIES_PER_BEAKER + (g & 3) + 1;  // within a 35-int row

    __shared__ int   xs[CHUNK * ROW_INTS];  // 8960 B raw X slice for this chunk
    __shared__ float semb[7 * COLOR_DIM];   // 3584 B embedding table (f32)

    semb[t] = emb[t];                       // 7*128 == NTHREADS: one f32 each
    const f32x4* __restrict__ sembf4 = reinterpret_cast<const f32x4*>(semb);
    f32x4* __restrict__ outf4 = reinterpret_cast<f32x4*>(out);

    for (int b0 = blockIdx.x * CHUNK; b0 < B; b0 += gridDim.x * CHUNK) {
        const int rows  = min(CHUNK, B - b0);
        const int nints = rows * ROW_INTS;

        __syncthreads();                    // xs reuse guard / semb ready
        for (int i = t; i < nints; i += NTHREADS)
            xs[i] = X[b0 * ROW_INTS + i];   // one coalesced 8960 B read
        __syncthreads();

        f32x4* __restrict__ dst = outf4 + (size_t)b0 * F4_PER_ROW + t;
        #pragma unroll 8
        for (int r = 0; r < rows; ++r) {
            const int id = xs[r * ROW_INTS + xoff];     // LDS broadcast (lgkm)
            const f32x4 v = sembf4[id * (COLOR_DIM / 4) + d4];  // LDS b128 (lgkm)
            dst[(size_t)r * F4_PER_ROW] = v;            // the ONLY vmcnt op in the loop
        }
    }
}

extern "C" void kernel_launch(void* const* d_in, const int* in_sizes, int n_in,
                              void* d_out, int out_size, void* d_ws, size_t ws_size,
                              hipStream_t stream) {
    const int*   X   = (const int*)d_in[0];     // [B, 35] int32
    const float* emb = (const float*)d_in[1];   // [7, 128] f32
    float*       out = (float*)d_out;           // [B, 3584] f32

    const int B = in_sizes[0] / ROW_INTS;       // 32768

    const int nchunks = (B + CHUNK - 1) / CHUNK;    // 512 for B=32768
    const int grid = (nchunks < 512) ? nchunks : 512;
    world_state_encoder_kernel<<<grid, NTHREADS, 0, stream>>>(X, emb, out, B);
}

// Round 7
// 96.058 us; speedup vs baseline: 1.0283x; 1.0103x over previous
//
#include <hip/hip_runtime.h>
#include <hip/hip_bf16.h>

// world_state_encoder: out[b, beaker*4+slot, :] = color_emb[X[b, beaker*5+1+slot], :]
// B=32768, 7 beakers, 4 color slots, D=128 -> out is [B, 3584] f32.
// Write-BW bound: ~470 MB out vs 4.6 MB idx in. Demonstrated ceiling:
// harness memset = 6.9 TB/s at OccupancyPercent=10.8 (!!) with 256-thread
// blocks. Our R3/R5/R6 (three different inner loops, all 896thr x 512blk =
// 28 waves/CU) all converge to 96.8-98.8 us = 4.85 TB/s -> the loop body is
// not the limit; the geometry is.
//
// R7 theory: too MANY concurrent store streams per CU thrash the store
// queue / L2 write path (28 waves x 8KB in flight ~ 229 KB/CU vs ~128 KB/CU
// L2 share). Memset proves 4 waves/CU with deep uninterrupted queues is the
// fast regime. Clone it: 256-thread blocks, grid=256 (1 block/CU, 4
// waves/CU). Block owns 128 rows: stage X slice (17.5 KB) + emb (3.5 KB) in
// LDS once, then each thread streams 448 independent f32x4 stores, unroll 8.
// j/896 division: j < 2^17, compiler magic-mul; VALU headroom is 20x.

#define NUM_BEAKERS 7
#define ENTRIES_PER_BEAKER 5
#define ROW_INTS (NUM_BEAKERS * ENTRIES_PER_BEAKER)   // 35
#define COLOR_DIM 128
#define GROUPS 28                                     // 7 beakers * 4 color slots
#define F4_PER_ROW (GROUPS * COLOR_DIM / 4)           // 896 float4 per row
#define NTHREADS 256                                  // memset-clone geometry
#define CHUNK 128                                     // rows per block (B/grid)

typedef float f32x4 __attribute__((ext_vector_type(4)));

__global__ __launch_bounds__(NTHREADS, 1) void world_state_encoder_kernel(
        const int* __restrict__ X,          // [B, 35] int32
        const float* __restrict__ emb,      // [7, 128] f32
        float* __restrict__ out,            // [B, 3584] f32
        int B) {
    const int tid = threadIdx.x;            // 0..255

    __shared__ int   xs[CHUNK * ROW_INTS];  // 17920 B raw X slice
    __shared__ float semb[7 * COLOR_DIM];   // 3584 B embedding table

    const f32x4* __restrict__ sembf4 = reinterpret_cast<const f32x4*>(semb);
    f32x4* __restrict__ outf4 = reinterpret_cast<f32x4*>(out);

    for (int i = tid; i < 7 * COLOR_DIM; i += NTHREADS)
        semb[i] = emb[i];

    for (int b0 = blockIdx.x * CHUNK; b0 < B; b0 += gridDim.x * CHUNK) {
        const int rows  = min(CHUNK, B - b0);
        const int nints = rows * ROW_INTS;

        __syncthreads();                    // xs reuse guard / semb ready
        for (int i = tid; i < nints; i += NTHREADS)
            xs[i] = X[b0 * ROW_INTS + i];   // one coalesced 17.5 KB read
        __syncthreads();

        f32x4* __restrict__ dst = outf4 + (size_t)b0 * F4_PER_ROW;
        const int nj = rows * F4_PER_ROW;   // 114688 for full chunk
        #pragma unroll 8
        for (int j = tid; j < nj; j += NTHREADS) {
            const int r  = j / F4_PER_ROW;          // magic-mul, j < 2^17
            const int t  = j - r * F4_PER_ROW;      // 0..895
            const int g  = t >> 5;                  // 0..27
            const int d4 = t & 31;
            const int xo = (g >> 2) * ENTRIES_PER_BEAKER + (g & 3) + 1;
            const int id = xs[r * ROW_INTS + xo];   // LDS, ~2 addrs per wave
            const f32x4 v = sembf4[id * (COLOR_DIM / 4) + d4];
            dst[j] = v;                             // 4 KB contiguous per block-iter
        }
    }
}

extern "C" void kernel_launch(void* const* d_in, const int* in_sizes, int n_in,
                              void* d_out, int out_size, void* d_ws, size_t ws_size,
                              hipStream_t stream) {
    const int*   X   = (const int*)d_in[0];     // [B, 35] int32
    const float* emb = (const float*)d_in[1];   // [7, 128] f32
    float*       out = (float*)d_out;           // [B, 3584] f32

    const int B = in_sizes[0] / ROW_INTS;       // 32768

    const int nchunks = (B + CHUNK - 1) / CHUNK;    // 256 for B=32768
    const int grid = (nchunks < 256) ? nchunks : 256;  // 1 block/CU, 4 waves/CU
    world_state_encoder_kernel<<<grid, NTHREADS, 0, stream>>>(X, emb, out, B);
}